// Round 11
// baseline (1879.933 us; speedup 1.0000x reference)
//
#include <hip/hip_runtime.h>
#include <hip/hip_bf16.h>

#define B_   512
#define L_   64
#define D_   16
#define H_   256
#define V_   512
#define STEPS_ 64
#define DT_  0.984375f
#define LOSC 2048.0f          // lo-term scale 2^11
#define LOSC_INV (1.0f/2048.0f)

typedef _Float16 half_t;
typedef __attribute__((ext_vector_type(8))) _Float16 half8;
typedef __attribute__((ext_vector_type(4))) float f32x4;

__device__ __forceinline__ void split16(float x, half_t& hi, half_t& lo) {
    half_t h = (half_t)x;
    hi = h;
    lo = (half_t)((x - (float)h) * LOSC);
}

// ---------------- prep kernels ----------------

// Pack W [N][K] fp32 into MFMA B-fragment order, f16 hi + scaled-lo:
// slot idx = ((g*Kc + c)*64 + l)*8 + j  <-  W[g*16 + (l&15)][c*32 + (l>>4)*8 + j]
__global__ void pack_frag_kernel(const float* __restrict__ src, half_t* __restrict__ hi,
                                 half_t* __restrict__ lo, int Kc, int K, int total) {
    int idx = blockIdx.x * 256 + threadIdx.x;
    if (idx >= total) return;
    int j = idx & 7;
    int l = (idx >> 3) & 63;
    int gc = idx >> 9;
    int c = gc % Kc, g = gc / Kc;
    int n = (g << 4) + (l & 15);
    int k = (c << 5) + ((l >> 4) << 3) + j;
    float w = src[n * K + k];
    half_t h, lw;
    split16(w, h, lw);
    hi[idx] = h;
    lo[idx] = lw;
}

// Same, but W pre-scaled by per-k vector (g folded in); hi/lo outputs.
__global__ void pack_frag_scaled2_kernel(const float* __restrict__ src,
                                         const float* __restrict__ scale,
                                         half_t* __restrict__ hi, half_t* __restrict__ lo,
                                         int Kc, int K, int total) {
    int idx = blockIdx.x * 256 + threadIdx.x;
    if (idx >= total) return;
    int j = idx & 7;
    int l = (idx >> 3) & 63;
    int gc = idx >> 9;
    int c = gc % Kc, g = gc / Kc;
    int n = (g << 4) + (l & 15);
    int k = (c << 5) + ((l >> 4) << 3) + j;
    float w = src[n * K + k] * scale[k];
    half_t h, lw;
    split16(w, h, lw);
    hi[idx] = h;
    lo[idx] = lw;
}

// Scaled, hi only (for W3g).
__global__ void pack_frag_scaled1_kernel(const float* __restrict__ src,
                                         const float* __restrict__ scale,
                                         half_t* __restrict__ hi,
                                         int Kc, int K, int total) {
    int idx = blockIdx.x * 256 + threadIdx.x;
    if (idx >= total) return;
    int j = idx & 7;
    int l = (idx >> 3) & 63;
    int gc = idx >> 9;
    int c = gc % Kc, g = gc / Kc;
    int n = (g << 4) + (l & 15);
    int k = (c << 5) + ((l >> 4) << 3) + j;
    hi[idx] = (half_t)(src[n * K + k] * scale[k]);
}

// cg[n] = sum_k g[k]*W[n,k];  cb[n] = sum_k be[k]*W[n,k] + b[n]
__global__ void colvec_kernel(const float* __restrict__ W, const float* __restrict__ g,
                              const float* __restrict__ be, const float* __restrict__ b,
                              float* __restrict__ cg, float* __restrict__ cb, int N, int K) {
    int n = blockIdx.x * 4 + (threadIdx.x >> 6);
    if (n >= N) return;
    int l = threadIdx.x & 63;
    float sg = 0.f, sb = 0.f;
    for (int k = l; k < K; k += 64) {
        float w = W[n * K + k];
        sg += g[k] * w;
        sb += be[k] * w;
    }
    #pragma unroll
    for (int o = 32; o; o >>= 1) { sg += __shfl_xor(sg, o); sb += __shfl_xor(sb, o); }
    if (l == 0) { cg[n] = sg; cb[n] = sb + b[n]; }
}

// h0 = tanh(X0 @ W0^T + b0)
__global__ void h0_kernel(const float* __restrict__ coeffs, const float* __restrict__ W0,
                          const float* __restrict__ b0, float* __restrict__ hout) {
    int b = blockIdx.x;
    int hh = threadIdx.x;
    float acc = b0[hh];
    #pragma unroll
    for (int d = 0; d < 16; d++)
        acc += coeffs[b * ((L_ - 1) * 4 * D_) + d] * W0[hh * 16 + d];
    hout[b * H_ + hh] = tanhf(acc);
}

// ---------------- per-step kernel 1: fused MLP (gemm1 recompute + gemm2) ----------------
// Grid (16,8) = 128 blocks, 512 threads. Block = 32 rows; GEMM1 computed full-width
// (t1[32x512] block-local, LN1 stats in-block), GEMM2 on 64-col slice -> t2 frags + stats2.
__global__ __launch_bounds__(512) void mlpf_kernel(
    const float* __restrict__ hptr,
    const half_t* __restrict__ W1h, const half_t* __restrict__ W1l,
    const float* __restrict__ b1,
    const half_t* __restrict__ W2gh, const half_t* __restrict__ W2gl,
    const float* __restrict__ cg2, const float* __restrict__ cb2,
    half_t* __restrict__ t2, float* __restrict__ stats2, int sIdx)
{
    __shared__ __align__(16) half_t A1h[2 * 8 * 64 * 8];   // 16 KB
    __shared__ __align__(16) half_t A1l[2 * 8 * 64 * 8];   // 16 KB
    __shared__ float zs[32][522];                          // 66.8 KB (t1 fp32, full width)
    __shared__ __align__(16) half_t A2[2 * 16 * 64 * 8];   // 32 KB (raw t1 f16 frags)
    __shared__ float mr[32], rrs[32];
    const int tid = threadIdx.x, w = tid >> 6, l = tid & 63;
    const int row0 = blockIdx.x * 32, col0 = blockIdx.y * 64;
    const int mf = w & 1;

    // 1. load h rows -> A1 hi/lo fragments
    {
        int gm = w & 1;
        #pragma unroll
        for (int cc = 0; cc < 2; cc++) {
            int c = ((w >> 1) << 1) + cc;
            const float* src = hptr + (row0 + (gm << 4) + (l & 15)) * H_ + (c << 5) + ((l >> 4) << 3);
            float4 x = *(const float4*)src;
            float4 y = *(const float4*)(src + 4);
            float xx[8] = {x.x, x.y, x.z, x.w, y.x, y.y, y.z, y.w};
            half8 hv, lv;
            #pragma unroll
            for (int j = 0; j < 8; j++) { half_t a, b; split16(xx[j], a, b); hv[j] = a; lv[j] = b; }
            int base = (((gm << 3) + c) * 64 + l) * 8;
            *(half8*)&A1h[base] = hv;
            *(half8*)&A1l[base] = lv;
        }
    }
    __syncthreads();

    // 2. GEMM1 full-width: wave = (mf, 8 gn's); gn = (w>>1)*8 + i
    f32x4 acc[8], accl[8];
    #pragma unroll
    for (int i = 0; i < 8; i++) { acc[i] = (f32x4){0,0,0,0}; accl[i] = (f32x4){0,0,0,0}; }
    for (int c = 0; c < 8; c++) {
        half8 ah = *(const half8*)&A1h[(((mf << 3) + c) * 64 + l) * 8];
        half8 al = *(const half8*)&A1l[(((mf << 3) + c) * 64 + l) * 8];
        #pragma unroll
        for (int i = 0; i < 8; i++) {
            int gn = ((w >> 1) << 3) + i;
            half8 bh = *(const half8*)&W1h[(((gn << 3) + c) * 64 + l) * 8];
            half8 bl = *(const half8*)&W1l[(((gn << 3) + c) * 64 + l) * 8];
            acc[i]  = __builtin_amdgcn_mfma_f32_16x16x32_f16(ah, bh, acc[i],  0, 0, 0);
            accl[i] = __builtin_amdgcn_mfma_f32_16x16x32_f16(ah, bl, accl[i], 0, 0, 0);
            accl[i] = __builtin_amdgcn_mfma_f32_16x16x32_f16(al, bh, accl[i], 0, 0, 0);
        }
    }
    // 3. bias + tanh -> zs (each wave's (rows x cols) region is disjoint; no sync needed)
    #pragma unroll
    for (int i = 0; i < 8; i++) {
        int gn = ((w >> 1) << 3) + i;
        int col = (gn << 4) + (l & 15);
        float bb = b1[col];
        #pragma unroll
        for (int j = 0; j < 4; j++)
            zs[(mf << 4) + ((l >> 4) << 2) + j][col] = tanhf(acc[i][j] + accl[i][j] * LOSC_INV + bb);
    }
    __syncthreads();

    // 4. LN1 row stats (full row, in-block) + pack raw t1 -> A2 f16 frags
    {
        int r = tid >> 4, q = tid & 15;
        float s = 0.f, ss = 0.f;
        for (int k = 0; k < 32; k++) {           // cols q + 16k: conflict-free
            float v = zs[r][q + (k << 4)];
            s += v; ss += v * v;
        }
        #pragma unroll
        for (int o = 8; o; o >>= 1) { s += __shfl_xor(s, o); ss += __shfl_xor(ss, o); }
        if (q == 0) {
            float m = s * (1.f / 512.f);
            mr[r] = m;
            rrs[r] = rsqrtf(ss * (1.f / 512.f) - m * m + 1e-5f);
        }
    }
    #pragma unroll
    for (int u = 0; u < 4; u++) {
        int slot = (u << 9) + tid;               // 0..2047 = [gm 2][c 16][l 64]
        int gm = slot >> 10, rem = slot & 1023;
        int c = rem >> 6, ll = rem & 63;
        const float* srcz = &zs[(gm << 4) + (ll & 15)][(c << 5) + ((ll >> 4) << 3)];
        half8 hv;
        #pragma unroll
        for (int j = 0; j < 8; j++) hv[j] = (half_t)srcz[j];
        *(half8*)&A2[slot << 3] = hv;
    }
    __syncthreads();

    // 5. GEMM2 on 64-col slice: wave = (mf, nf = w>>1)
    const int nf = w >> 1;
    const int gnO = (col0 >> 4) + nf;
    f32x4 a2 = {0.f, 0.f, 0.f, 0.f}, a2l = {0.f, 0.f, 0.f, 0.f};
    for (int c = 0; c < 16; c++) {
        half8 ah = *(const half8*)&A2[(((mf << 4) + c) * 64 + l) * 8];
        half8 bh = *(const half8*)&W2gh[(((gnO << 4) + c) * 64 + l) * 8];
        half8 bl = *(const half8*)&W2gl[(((gnO << 4) + c) * 64 + l) * 8];
        a2  = __builtin_amdgcn_mfma_f32_16x16x32_f16(ah, bh, a2,  0, 0, 0);
        a2l = __builtin_amdgcn_mfma_f32_16x16x32_f16(ah, bl, a2l, 0, 0, 0);
    }
    __syncthreads();
    // 6. affine LN1 fix + bias + tanh -> zs[.][0..64)
    {
        int colb = (nf << 4) + (l & 15);
        int col = col0 + colb;
        float cgv = cg2[col], cbv = cb2[col];
        #pragma unroll
        for (int j = 0; j < 4; j++) {
            int r = (mf << 4) + ((l >> 4) << 2) + j;
            float S = a2[j] + a2l[j] * LOSC_INV;
            float v = rrs[r] * S - mr[r] * rrs[r] * cgv + cbv;
            zs[r][colb] = tanhf(v);
        }
    }
    __syncthreads();
    // 7. LN2 partial stats -> global (unique slot) + pack t2 frags
    {
        int r = tid >> 4, c0 = (tid & 15) << 2;
        float s = 0.f, ss = 0.f;
        #pragma unroll
        for (int j = 0; j < 4; j++) { float v = zs[r][c0 + j]; s += v; ss += v * v; }
        #pragma unroll
        for (int o = 8; o; o >>= 1) { s += __shfl_xor(s, o); ss += __shfl_xor(ss, o); }
        if ((tid & 15) == 0) {
            float* st = stats2 + (((sIdx << 3) + blockIdx.y) * 512 + row0 + r) * 2;
            st[0] = s; st[1] = ss;
        }
    }
    if (tid < 256) {
        int p = tid >> 6;
        int gmp = p & 1, cp = p >> 1;
        half8 hv;
        #pragma unroll
        for (int j = 0; j < 8; j++)
            hv[j] = (half_t)zs[(gmp << 4) + (l & 15)][(cp << 5) + ((l >> 4) << 3) + j];
        *(half8*)&t2[((((row0 >> 4) + gmp) * 16 + (col0 >> 5) + cp) * 64 + l) * 8] = hv;
    }
}

// ---------------- per-step kernel 2: stage 3 ----------------
// vf = rv2*(t2 @ W3g^T) - m2*rv2*cg3 + cb3;  h += dt*(vf . dX).
// 512 blocks = 16 row-groups (32 rows) x 32 col-groups; t2 slice staged in LDS once.
__global__ __launch_bounds__(512) void stage3_kernel(
    const half_t* __restrict__ t2, const float* __restrict__ stats2,
    const half_t* __restrict__ W3gh, const float* __restrict__ cg3,
    const float* __restrict__ cb3, const float* __restrict__ coeffs,
    float* __restrict__ hbuf, int ii, float frac, int sIdx)
{
    __shared__ __align__(16) half_t Ah[2 * 16 * 64 * 8];  // 32 KB (t2 slice)
    __shared__ float dxs[32][17];
    __shared__ float mvals[32], rvals[32];
    const int tid = threadIdx.x, w = tid >> 6, l = tid & 63;
    const int rg = blockIdx.x >> 5;      // 0..15 (32 rows)
    const int cgi = blockIdx.x & 31;     // 0..31 (128 cols)
    const int row0 = rg << 5;
    const int gn = (cgi << 3) + w;
    const int gm0 = rg << 1;

    // spline derivative for the block's 32 rows
    {
        int r = tid >> 4, d = tid & 15;
        int base = ((row0 + r) * (L_ - 1) + ii) * 64 + d;
        float c1 = coeffs[base + 16], c2 = coeffs[base + 32], c3 = coeffs[base + 48];
        dxs[r][d] = c1 + 2.0f * frac * c2 + 3.0f * (frac * frac) * c3;
    }
    // finalize LN2 stats for 32 rows
    if (tid < 32) {
        float s = 0.f, ss = 0.f;
        #pragma unroll
        for (int p = 0; p < 8; p++) {
            const float* st = stats2 + (((sIdx << 3) + p) * 512 + row0 + tid) * 2;
            s += st[0]; ss += st[1];
        }
        float m = s * (1.f / 512.f);
        mvals[tid] = m;
        rvals[tid] = rsqrtf(ss * (1.f / 512.f) - m * m + 1e-5f);
    }
    // stage t2 slice (2 gm x 16 c) into LDS
    #pragma unroll
    for (int u = 0; u < 4; u++) {
        int slot = (u << 9) + tid;               // [gm 2][c 16][l 64]
        int gmi = slot >> 10, rem = slot & 1023;
        int c = rem >> 6, ll = rem & 63;
        *(half8*)&Ah[slot << 3] =
            *(const half8*)&t2[((((gm0 + gmi) << 4) + c) * 64 + ll) * 8];
    }
    __syncthreads();

    f32x4 acc0 = {0.f, 0.f, 0.f, 0.f}, acc1 = {0.f, 0.f, 0.f, 0.f};
    for (int c = 0; c < 16; c++) {
        half8 bh = *(const half8*)&W3gh[(((gn << 4) + c) * 64 + l) * 8];
        half8 a0 = *(const half8*)&Ah[((c) * 64 + l) * 8];
        half8 a1 = *(const half8*)&Ah[((16 + c) * 64 + l) * 8];
        acc0 = __builtin_amdgcn_mfma_f32_16x16x32_f16(a0, bh, acc0, 0, 0, 0);
        acc1 = __builtin_amdgcn_mfma_f32_16x16x32_f16(a1, bh, acc1, 0, 0, 0);
    }

    // epilogue: affine LN2 fix + dX contraction + 16-lane reduce + unique-writer h RMW
    const int d = l & 15;
    const int o = (gn << 4) + d;
    const float cgv = cg3[o], cbv = cb3[o];
    #pragma unroll
    for (int mf = 0; mf < 2; mf++) {
        f32x4 a = mf ? acc1 : acc0;
        #pragma unroll
        for (int j = 0; j < 4; j++) {
            int rl = (mf << 4) + ((l >> 4) << 2) + j;
            float vf = rvals[rl] * a[j] - mvals[rl] * rvals[rl] * cgv + cbv;
            float s = vf * dxs[rl][d];
            s += __shfl_xor(s, 1);
            s += __shfl_xor(s, 2);
            s += __shfl_xor(s, 4);
            s += __shfl_xor(s, 8);
            if (d == 0) hbuf[(row0 + rl) * H_ + gn] += s * DT_;
        }
    }
}

// ---------------- launch ----------------

extern "C" void kernel_launch(void* const* d_in, const int* in_sizes, int n_in,
                              void* d_out, int out_size, void* d_ws, size_t ws_size,
                              hipStream_t stream) {
    const float* coeffs = (const float*)d_in[0];
    const float* W0  = (const float*)d_in[1];
    const float* b0  = (const float*)d_in[2];
    const float* W1  = (const float*)d_in[3];
    const float* b1  = (const float*)d_in[4];
    const float* g1  = (const float*)d_in[5];
    const float* be1 = (const float*)d_in[6];
    const float* W2  = (const float*)d_in[7];
    const float* b2  = (const float*)d_in[8];
    const float* g2  = (const float*)d_in[9];
    const float* be2 = (const float*)d_in[10];
    const float* W3  = (const float*)d_in[11];
    const float* b3  = (const float*)d_in[12];

    char* w = (char*)d_ws;
    float*  hbuf   = (float*)(w);                      // 512 KB
    half_t* t2     = (half_t*)(w + 524288);            // 512 KB
    half_t* W1h    = (half_t*)(w + 1048576);           // 256 KB
    half_t* W1l    = (half_t*)(w + 1310720);           // 256 KB
    half_t* W2gh   = (half_t*)(w + 1572864);           // 512 KB
    half_t* W2gl   = (half_t*)(w + 2097152);           // 512 KB
    half_t* W3gh   = (half_t*)(w + 2621440);           // 4 MB
    float*  cg2    = (float*)(w + 6815744);            // 2 KB
    float*  cb2    = (float*)(w + 6817792);            // 2 KB
    float*  cg3    = (float*)(w + 6819840);            // 16 KB
    float*  cb3    = (float*)(w + 6836224);            // 16 KB
    float*  stats2 = (float*)(w + 6852608);            // 2 MB

    pack_frag_kernel<<<512, 256, 0, stream>>>(W1, W1h, W1l, 8, H_, V_ * H_);
    pack_frag_scaled2_kernel<<<1024, 256, 0, stream>>>(W2, g1, W2gh, W2gl, 16, V_, V_ * V_);
    pack_frag_scaled1_kernel<<<8192, 256, 0, stream>>>(W3, g2, W3gh, 16, V_, (H_ * D_) * V_);
    colvec_kernel<<<V_ / 4, 256, 0, stream>>>(W2, g1, be1, b2, cg2, cb2, V_, V_);
    colvec_kernel<<<(H_ * D_) / 4, 256, 0, stream>>>(W3, g2, be2, b3, cg3, cb3, H_ * D_, V_);
    h0_kernel<<<B_, H_, 0, stream>>>(coeffs, W0, b0, hbuf);

    for (int s = 0; s < STEPS_; s++) {
        float t = (float)s * 0.984375f;      // exact in fp32
        int ii = (int)t;
        if (ii > L_ - 2) ii = L_ - 2;
        float frac = t - (float)ii;
        mlpf_kernel<<<dim3(16, 8), 512, 0, stream>>>(hbuf, W1h, W1l, b1,
                                                     W2gh, W2gl, cg2, cb2,
                                                     t2, stats2, s);
        stage3_kernel<<<512, 512, 0, stream>>>(t2, stats2, W3gh, cg3, cb3, coeffs,
                                               hbuf, ii, frac, s);
    }

    hipMemcpyAsync(d_out, hbuf, (size_t)B_ * H_ * sizeof(float),
                   hipMemcpyDeviceToDevice, stream);
}

// Round 12
// 1500.817 us; speedup vs baseline: 1.2526x; 1.2526x over previous
//
#include <hip/hip_runtime.h>
#include <hip/hip_bf16.h>

#define B_   512
#define L_   64
#define D_   16
#define H_   256
#define V_   512
#define STEPS_ 64
#define DT_  0.984375f
#define LOSC 2048.0f          // lo-term scale 2^11
#define LOSC_INV (1.0f/2048.0f)

typedef _Float16 half_t;
typedef __attribute__((ext_vector_type(8))) _Float16 half8;
typedef __attribute__((ext_vector_type(4))) float f32x4;

__device__ __forceinline__ void split16(float x, half_t& hi, half_t& lo) {
    half_t h = (half_t)x;
    hi = h;
    lo = (half_t)((x - (float)h) * LOSC);
}

// ---------------- prep kernels (fused) ----------------

// One kernel packs all three weights into MFMA B-fragment order.
// slot idx = ((g*Kc + c)*64 + l)*8 + j  <-  Wsrc[g*16 + (l&15)][c*32 + (l>>4)*8 + j]
// bid <  512        : W1 (K=256, Kc=8), hi/lo, unscaled
// bid <  512+1024   : W2 (K=512, Kc=16), hi/lo, scaled by g1
// else (8192 blocks): W3 (K=512, Kc=16), hi only, scaled by g2
__global__ void pack_all_kernel(
    const float* __restrict__ W1, half_t* __restrict__ W1h, half_t* __restrict__ W1l,
    const float* __restrict__ W2, const float* __restrict__ g1,
    half_t* __restrict__ W2gh, half_t* __restrict__ W2gl,
    const float* __restrict__ W3, const float* __restrict__ g2,
    half_t* __restrict__ W3gh)
{
    int bid = blockIdx.x, tid = threadIdx.x;
    const float* src; const float* scale; half_t* hi; half_t* lo;
    int idx, Kc, K;
    if (bid < 512) {
        idx = bid * 256 + tid; src = W1; scale = nullptr; hi = W1h; lo = W1l; Kc = 8; K = 256;
    } else if (bid < 1536) {
        idx = (bid - 512) * 256 + tid; src = W2; scale = g1; hi = W2gh; lo = W2gl; Kc = 16; K = 512;
    } else {
        idx = (bid - 1536) * 256 + tid; src = W3; scale = g2; hi = W3gh; lo = nullptr; Kc = 16; K = 512;
    }
    int j = idx & 7;
    int l = (idx >> 3) & 63;
    int gc = idx >> 9;
    int c = gc % Kc, g = gc / Kc;
    int n = (g << 4) + (l & 15);
    int k = (c << 5) + ((l >> 4) << 3) + j;
    float w = src[n * K + k];
    if (scale) w *= scale[k];
    if (lo) {
        half_t h, lw;
        split16(w, h, lw);
        hi[idx] = h;
        lo[idx] = lw;
    } else {
        hi[idx] = (half_t)w;
    }
}

// cg[n] = sum_k g[k]*W[n,k];  cb[n] = sum_k be[k]*W[n,k] + b[n]
// bid < 128: W2/g1/be1/b2 -> cg2/cb2 (N=512).  else: W3/g2/be2/b3 -> cg3/cb3 (N=4096).
__global__ void colvec_all_kernel(
    const float* __restrict__ W2, const float* __restrict__ g1,
    const float* __restrict__ be1, const float* __restrict__ b2,
    float* __restrict__ cg2, float* __restrict__ cb2,
    const float* __restrict__ W3, const float* __restrict__ g2,
    const float* __restrict__ be2, const float* __restrict__ b3,
    float* __restrict__ cg3, float* __restrict__ cb3)
{
    int bid = blockIdx.x;
    const float *W, *g, *be, *b; float *cg, *cb; int n;
    if (bid < 128) { W = W2; g = g1; be = be1; b = b2; cg = cg2; cb = cb2; n = bid * 4 + (threadIdx.x >> 6); }
    else           { W = W3; g = g2; be = be2; b = b3; cg = cg3; cb = cb3; n = (bid - 128) * 4 + (threadIdx.x >> 6); }
    int l = threadIdx.x & 63;
    float sg = 0.f, sb = 0.f;
    for (int k = l; k < V_; k += 64) {
        float w = W[n * V_ + k];
        sg += g[k] * w;
        sb += be[k] * w;
    }
    #pragma unroll
    for (int o = 32; o; o >>= 1) { sg += __shfl_xor(sg, o); sb += __shfl_xor(sb, o); }
    if (l == 0) { cg[n] = sg; cb[n] = sb + b[n]; }
}

// h0 = tanh(X0 @ W0^T + b0)
__global__ void h0_kernel(const float* __restrict__ coeffs, const float* __restrict__ W0,
                          const float* __restrict__ b0, float* __restrict__ hout) {
    int b = blockIdx.x;
    int hh = threadIdx.x;
    float acc = b0[hh];
    #pragma unroll
    for (int d = 0; d < 16; d++)
        acc += coeffs[b * ((L_ - 1) * 4 * D_) + d] * W0[hh * 16 + d];
    hout[b * H_ + hh] = tanhf(acc);
}

// ---------------- per-step kernels ----------------

// GEMM1: t1 = tanh(h @ W1^T + b1) -> single-f16 A-fragments + per-block row stats.
// Grid (16,8), 512 threads; block = 32 rows x 64 cols.
__global__ __launch_bounds__(512) void gemm1_kernel(
    const float* __restrict__ hptr,
    const half_t* __restrict__ W1h, const half_t* __restrict__ W1l,
    const float* __restrict__ b1, half_t* __restrict__ t1,
    float* __restrict__ stats1, int sIdx)
{
    __shared__ __align__(16) half_t Ah[2 * 8 * 64 * 8];   // 16 KB
    __shared__ __align__(16) half_t Al[2 * 8 * 64 * 8];   // 16 KB
    __shared__ float zs[32][65];                          // 8.3 KB
    const int tid = threadIdx.x, w = tid >> 6, l = tid & 63;
    const int row0 = blockIdx.x * 32, col0 = blockIdx.y * 64;

    // stage h rows as f16 hi/lo fragments
    {
        int gm = w & 1;
        #pragma unroll
        for (int cc = 0; cc < 2; cc++) {
            int c = ((w >> 1) << 1) + cc;
            const float* src = hptr + (row0 + (gm << 4) + (l & 15)) * H_ + (c << 5) + ((l >> 4) << 3);
            float4 x = *(const float4*)src;
            float4 y = *(const float4*)(src + 4);
            float xx[8] = {x.x, x.y, x.z, x.w, y.x, y.y, y.z, y.w};
            half8 hv, lv;
            #pragma unroll
            for (int j = 0; j < 8; j++) { half_t a, b; split16(xx[j], a, b); hv[j] = a; lv[j] = b; }
            int base = (((gm << 3) + c) * 64 + l) * 8;
            *(half8*)&Ah[base] = hv;
            *(half8*)&Al[base] = lv;
        }
    }
    __syncthreads();

    const int mf = w & 1, nf = w >> 1;
    const int gn = (col0 >> 4) + nf;
    f32x4 acc = {0.f, 0.f, 0.f, 0.f}, accl = {0.f, 0.f, 0.f, 0.f};
    for (int c = 0; c < 8; c++) {
        half8 ah = *(const half8*)&Ah[(((mf << 3) + c) * 64 + l) * 8];
        half8 al = *(const half8*)&Al[(((mf << 3) + c) * 64 + l) * 8];
        half8 bh = *(const half8*)&W1h[(((gn << 3) + c) * 64 + l) * 8];
        half8 bl = *(const half8*)&W1l[(((gn << 3) + c) * 64 + l) * 8];
        acc  = __builtin_amdgcn_mfma_f32_16x16x32_f16(ah, bh, acc,  0, 0, 0);
        accl = __builtin_amdgcn_mfma_f32_16x16x32_f16(ah, bl, accl, 0, 0, 0);
        accl = __builtin_amdgcn_mfma_f32_16x16x32_f16(al, bh, accl, 0, 0, 0);
    }
    {
        int colb = (nf << 4) + (l & 15);
        float bb = b1[col0 + colb];
        #pragma unroll
        for (int j = 0; j < 4; j++) {
            float v = acc[j] + accl[j] * LOSC_INV + bb;
            zs[(mf << 4) + ((l >> 4) << 2) + j][colb] = tanhf(v);
        }
    }
    __syncthreads();
    // per-block row stats over the 64 local cols -> unique slot (no atomics)
    {
        int r = tid >> 4, c0 = (tid & 15) << 2;
        float s = 0.f, ss = 0.f;
        #pragma unroll
        for (int j = 0; j < 4; j++) { float v = zs[r][c0 + j]; s += v; ss += v * v; }
        #pragma unroll
        for (int o = 8; o; o >>= 1) { s += __shfl_xor(s, o); ss += __shfl_xor(ss, o); }
        if ((tid & 15) == 0) {
            float* st = stats1 + (((sIdx << 3) + blockIdx.y) * 512 + row0 + r) * 2;
            st[0] = s; st[1] = ss;
        }
    }
    // pack tanh output into single-f16 A-fragments for gemm2
    if (tid < 256) {
        int p = tid >> 6;              // (gm' 2) x (c' 2)
        int gmp = p & 1, cp = p >> 1;
        half8 hv;
        #pragma unroll
        for (int j = 0; j < 8; j++)
            hv[j] = (half_t)zs[(gmp << 4) + (l & 15)][(cp << 5) + ((l >> 4) << 3) + j];
        *(half8*)&t1[((((row0 >> 4) + gmp) * 16 + (col0 >> 5) + cp) * 64 + l) * 8] = hv;
    }
}

// GEMM2: t2 = tanh(rv*(t1 @ W2g^T) - m*rv*cg2 + cb2) -> single-f16 fragments + stats.
// LN folded: W2g = g1*W2 (hi/lo), cg2/cb2 precomputed. Raw t1 frags read from L2.
// Grid (16,8), 512 threads; block = 32 rows x 64 cols.
__global__ __launch_bounds__(512) void gemm2_kernel(
    const half_t* __restrict__ t1, const float* __restrict__ stats1,
    const half_t* __restrict__ W2gh, const half_t* __restrict__ W2gl,
    const float* __restrict__ cg2, const float* __restrict__ cb2,
    half_t* __restrict__ t2, float* __restrict__ stats2, int sIdx)
{
    __shared__ float zs[32][65];
    __shared__ float mr[32], rrs[32];
    const int tid = threadIdx.x, w = tid >> 6, l = tid & 63;
    const int row0 = blockIdx.x * 32, col0 = blockIdx.y * 64;

    // prologue: finalize LN1 stats for our 32 rows
    if (tid < 32) {
        float s = 0.f, ss = 0.f;
        #pragma unroll
        for (int p = 0; p < 8; p++) {
            const float* st = stats1 + (((sIdx << 3) + p) * 512 + row0 + tid) * 2;
            s += st[0]; ss += st[1];
        }
        float m = s * (1.f / 512.f);
        mr[tid] = m;
        rrs[tid] = rsqrtf(ss * (1.f / 512.f) - m * m + 1e-5f);
    }
    __syncthreads();

    const int mf = w & 1, nf = w >> 1;
    const int gn = (col0 >> 4) + nf;
    const int gmA = (row0 >> 4) + mf;
    f32x4 acc = {0.f, 0.f, 0.f, 0.f}, accl = {0.f, 0.f, 0.f, 0.f};
    for (int c = 0; c < 16; c++) {
        half8 ah = *(const half8*)&t1[((gmA * 16 + c) * 64 + l) * 8];
        half8 bh = *(const half8*)&W2gh[(((gn << 4) + c) * 64 + l) * 8];
        half8 bl = *(const half8*)&W2gl[(((gn << 4) + c) * 64 + l) * 8];
        acc  = __builtin_amdgcn_mfma_f32_16x16x32_f16(ah, bh, acc,  0, 0, 0);
        accl = __builtin_amdgcn_mfma_f32_16x16x32_f16(ah, bl, accl, 0, 0, 0);
    }
    {
        int colb = (nf << 4) + (l & 15);
        int col = col0 + colb;
        float cgv = cg2[col], cbv = cb2[col];
        #pragma unroll
        for (int j = 0; j < 4; j++) {
            int r = (mf << 4) + ((l >> 4) << 2) + j;
            float S = acc[j] + accl[j] * LOSC_INV;
            float v = rrs[r] * S - mr[r] * rrs[r] * cgv + cbv;
            zs[r][colb] = tanhf(v);
        }
    }
    __syncthreads();
    // stats epilogue (LN2 partials)
    {
        int r = tid >> 4, c0 = (tid & 15) << 2;
        float s = 0.f, ss = 0.f;
        #pragma unroll
        for (int j = 0; j < 4; j++) { float v = zs[r][c0 + j]; s += v; ss += v * v; }
        #pragma unroll
        for (int o = 8; o; o >>= 1) { s += __shfl_xor(s, o); ss += __shfl_xor(ss, o); }
        if ((tid & 15) == 0) {
            float* st = stats2 + (((sIdx << 3) + blockIdx.y) * 512 + row0 + r) * 2;
            st[0] = s; st[1] = ss;
        }
    }
    // pack t2 single-f16 frags
    if (tid < 256) {
        int p = tid >> 6;
        int gmp = p & 1, cp = p >> 1;
        half8 hv;
        #pragma unroll
        for (int j = 0; j < 8; j++)
            hv[j] = (half_t)zs[(gmp << 4) + (l & 15)][(cp << 5) + ((l >> 4) << 3) + j];
        *(half8*)&t2[((((row0 >> 4) + gmp) * 16 + (col0 >> 5) + cp) * 64 + l) * 8] = hv;
    }
}

// Stage 3: vf = rv2*(t2 @ W3g^T) - m2*rv2*cg3 + cb3;  h += dt*(vf . dX).
// 512 blocks = 16 row-groups (32 rows) x 32 col-groups (128 cols).
// Wave w owns n-group gn = cgi*8 + w (== hh); 2 m-frags; A read direct from L2.
// On the final step also writes h to the output buffer (replaces the d2d copy).
__global__ __launch_bounds__(512) void stage3_kernel(
    const half_t* __restrict__ t2, const float* __restrict__ stats2,
    const half_t* __restrict__ W3gh, const float* __restrict__ cg3,
    const float* __restrict__ cb3, const float* __restrict__ coeffs,
    float* __restrict__ hbuf, float* __restrict__ hout, int isFinal,
    int ii, float frac, int sIdx)
{
    __shared__ float dxs[32][17];        // 2.1 KB
    __shared__ float mvals[32], rvals[32];
    const int tid = threadIdx.x, w = tid >> 6, l = tid & 63;
    const int rg = blockIdx.x >> 5;      // 0..15 (32 rows)
    const int cgi = blockIdx.x & 31;     // 0..31 (128 cols)
    const int row0 = rg << 5;
    const int gn = (cgi << 3) + w;

    // spline derivative for the block's 32 rows (one element per thread)
    {
        int r = tid >> 4, d = tid & 15;
        int base = ((row0 + r) * (L_ - 1) + ii) * 64 + d;
        float c1 = coeffs[base + 16], c2 = coeffs[base + 32], c3 = coeffs[base + 48];
        dxs[r][d] = c1 + 2.0f * frac * c2 + 3.0f * (frac * frac) * c3;
    }
    // finalize LN2 stats for 32 rows
    if (tid < 32) {
        float s = 0.f, ss = 0.f;
        #pragma unroll
        for (int p = 0; p < 8; p++) {
            const float* st = stats2 + (((sIdx << 3) + p) * 512 + row0 + tid) * 2;
            s += st[0]; ss += st[1];
        }
        float m = s * (1.f / 512.f);
        mvals[tid] = m;
        rvals[tid] = rsqrtf(ss * (1.f / 512.f) - m * m + 1e-5f);
    }
    __syncthreads();

    const int gm0 = rg << 1;
    f32x4 acc0 = {0.f, 0.f, 0.f, 0.f}, acc1 = {0.f, 0.f, 0.f, 0.f};
    for (int c = 0; c < 16; c++) {
        half8 bh = *(const half8*)&W3gh[(((gn << 4) + c) * 64 + l) * 8];
        half8 a0 = *(const half8*)&t2[(((gm0 + 0) * 16 + c) * 64 + l) * 8];
        half8 a1 = *(const half8*)&t2[(((gm0 + 1) * 16 + c) * 64 + l) * 8];
        acc0 = __builtin_amdgcn_mfma_f32_16x16x32_f16(a0, bh, acc0, 0, 0, 0);
        acc1 = __builtin_amdgcn_mfma_f32_16x16x32_f16(a1, bh, acc1, 0, 0, 0);
    }

    // epilogue: affine LN fix + dX contraction + 16-lane reduce + unique-writer h RMW
    const int d = l & 15;
    const int o = (gn << 4) + d;
    const float cgv = cg3[o], cbv = cb3[o];
    #pragma unroll
    for (int mf = 0; mf < 2; mf++) {
        f32x4 a = mf ? acc1 : acc0;
        #pragma unroll
        for (int j = 0; j < 4; j++) {
            int rl = (mf << 4) + ((l >> 4) << 2) + j;
            float vf = rvals[rl] * a[j] - mvals[rl] * rvals[rl] * cgv + cbv;
            float s = vf * dxs[rl][d];
            s += __shfl_xor(s, 1);
            s += __shfl_xor(s, 2);
            s += __shfl_xor(s, 4);
            s += __shfl_xor(s, 8);
            if (d == 0) {
                int off = (row0 + rl) * H_ + gn;
                float nh = hbuf[off] + s * DT_;
                hbuf[off] = nh;
                if (isFinal) hout[off] = nh;
            }
        }
    }
}

// ---------------- launch ----------------

extern "C" void kernel_launch(void* const* d_in, const int* in_sizes, int n_in,
                              void* d_out, int out_size, void* d_ws, size_t ws_size,
                              hipStream_t stream) {
    const float* coeffs = (const float*)d_in[0];
    const float* W0  = (const float*)d_in[1];
    const float* b0  = (const float*)d_in[2];
    const float* W1  = (const float*)d_in[3];
    const float* b1  = (const float*)d_in[4];
    const float* g1  = (const float*)d_in[5];
    const float* be1 = (const float*)d_in[6];
    const float* W2  = (const float*)d_in[7];
    const float* b2  = (const float*)d_in[8];
    const float* g2  = (const float*)d_in[9];
    const float* be2 = (const float*)d_in[10];
    const float* W3  = (const float*)d_in[11];
    const float* b3  = (const float*)d_in[12];

    char* w = (char*)d_ws;
    float*  hbuf   = (float*)(w);                      // 512 KB
    half_t* t1     = (half_t*)(w + 524288);            // 512 KB
    half_t* t2     = (half_t*)(w + 1048576);           // 512 KB
    half_t* W1h    = (half_t*)(w + 1572864);           // 256 KB
    half_t* W1l    = (half_t*)(w + 1835008);           // 256 KB
    half_t* W2gh   = (half_t*)(w + 2097152);           // 512 KB
    half_t* W2gl   = (half_t*)(w + 2621440);           // 512 KB
    half_t* W3gh   = (half_t*)(w + 3145728);           // 4 MB
    float*  cg2    = (float*)(w + 7340032);            // 2 KB
    float*  cb2    = (float*)(w + 7342080);            // 2 KB
    float*  cg3    = (float*)(w + 7344128);            // 16 KB
    float*  cb3    = (float*)(w + 7360512);            // 16 KB
    float*  stats1 = (float*)(w + 7376896);            // 2 MB
    float*  stats2 = (float*)(w + 9474048);            // 2 MB   (ends ~11.6 MB)

    pack_all_kernel<<<512 + 1024 + 8192, 256, 0, stream>>>(
        W1, W1h, W1l, W2, g1, W2gh, W2gl, W3, g2, W3gh);
    colvec_all_kernel<<<128 + 1024, 256, 0, stream>>>(
        W2, g1, be1, b2, cg2, cb2, W3, g2, be2, b3, cg3, cb3);
    h0_kernel<<<B_, H_, 0, stream>>>(coeffs, W0, b0, hbuf);

    for (int s = 0; s < STEPS_; s++) {
        float t = (float)s * 0.984375f;      // exact in fp32
        int ii = (int)t;
        if (ii > L_ - 2) ii = L_ - 2;
        float frac = t - (float)ii;
        gemm1_kernel<<<dim3(16, 8), 512, 0, stream>>>(hbuf, W1h, W1l, b1, t1, stats1, s);
        gemm2_kernel<<<dim3(16, 8), 512, 0, stream>>>(t1, stats1, W2gh, W2gl,
                                                      cg2, cb2, t2, stats2, s);
        stage3_kernel<<<512, 512, 0, stream>>>(t2, stats2, W3gh, cg3, cb3, coeffs,
                                               hbuf, (float*)d_out,
                                               (s == STEPS_ - 1) ? 1 : 0,
                                               ii, frac, s);
    }
}